// Round 1
// 824.665 us; speedup vs baseline: 1.0515x; 1.0515x over previous
//
#include <hip/hip_runtime.h>

#define N_EDGES  1000000
#define N_NODES  100000
#define DIM      128

typedef float f32x4 __attribute__((ext_vector_type(4)));

// Workspace layout (uint32 element offsets into d_ws)
#define WS_COUNTS   0            // [100000] histogram (zeroed)
#define WS_CURSORS  100000       // [100000] scatter cursors (zeroed)
#define WS_CTR      200000       // [1]      global allocation cursor (zeroed)
#define WS_OFFSETS  200064       // [100000] group base offsets (order arbitrary)
#define WS_PAIRS    300064       // [1000000 x uint2] (edge_id, src_node) grouped by dst

__global__ void __launch_bounds__(256)
hist_kernel(const int* __restrict__ dst, unsigned* __restrict__ counts)
{
    int e = blockIdx.x * 256 + threadIdx.x;
    if (e < N_EDGES) atomicAdd(&counts[dst[e]], 1u);
}

// Group order in the sorted/pairs array is irrelevant for a segmented sum,
// so instead of a stable prefix-sum pipeline we allocate each node's group
// base with one wave-aggregated atomic on a single global cursor.
__global__ void __launch_bounds__(256)
alloc_offsets(const unsigned* __restrict__ counts, unsigned* __restrict__ offsets,
              unsigned* __restrict__ ctr)
{
    int n = blockIdx.x * 256 + threadIdx.x;
    int lane = threadIdx.x & 63;
    unsigned cnt = (n < N_NODES) ? counts[n] : 0u;

    // inclusive wave scan of cnt
    unsigned incl = cnt;
    #pragma unroll
    for (int off = 1; off < 64; off <<= 1) {
        unsigned v = __shfl_up(incl, off, 64);
        if (lane >= off) incl += v;
    }
    unsigned total = __shfl(incl, 63, 64);
    unsigned base = 0;
    if (lane == 63) base = atomicAdd(ctr, total);
    base = __shfl(base, 63, 64);
    if (n < N_NODES) offsets[n] = base + incl - cnt;
}

__global__ void __launch_bounds__(256)
scatter_kernel(const int* __restrict__ dst, const int* __restrict__ src,
               const unsigned* __restrict__ offsets, unsigned* __restrict__ cursors,
               uint2* __restrict__ pairs)
{
    int e = blockIdx.x * 256 + threadIdx.x;
    if (e >= N_EDGES) return;
    int d = dst[e];
    unsigned pos = offsets[d] + atomicAdd(&cursors[d], 1u);
    pairs[pos] = make_uint2((unsigned)e, (unsigned)src[e]);
}

__device__ __forceinline__ f32x4 ld_nt(const float* p)
{
    return __builtin_nontemporal_load(reinterpret_cast<const f32x4*>(p));
}
__device__ __forceinline__ f32x4 ld(const float* p)
{
    return *reinterpret_cast<const f32x4*>(p);
}

// One wave per node. 32 lanes own 4 columns each (float4); the two wave
// halves process even/odd edges of the node's group, unrolled 2x, so four
// independent edge rows are in flight per iteration. Halves are combined
// with a single shfl_xor(32) pass at the end.
// y is streamed non-temporally (512 MB/call, zero reuse) so the 51 MB x
// table stays L2/L3-resident for the gathers.
__global__ void __launch_bounds__(256)
gather_reduce(const float* __restrict__ x, const float* __restrict__ y,
              const float* __restrict__ coeffs,
              const unsigned* __restrict__ offsets, const unsigned* __restrict__ counts,
              const uint2* __restrict__ pairs, float* __restrict__ out)
{
    int wave = threadIdx.x >> 6;
    int lane = threadIdx.x & 63;
    int n = blockIdx.x * 4 + wave;
    if (n >= N_NODES) return;

    int half = lane >> 5;          // 0: even edges, 1: odd edges
    int l    = lane & 31;
    int col  = l * 4;              // cols [4l, 4l+3], all in segment l>>3
    float c  = coeffs[l >> 3];

    unsigned start = offsets[n];
    unsigned cnt   = counts[n];
    unsigned end   = start + cnt;

    float a0 = 0.f, a1 = 0.f, a2 = 0.f, a3 = 0.f;
    float b0 = 0.f, b1 = 0.f, b2 = 0.f, b3 = 0.f;

    unsigned j = start + half;
    for (; j + 2 < end; j += 4) {
        uint2 p0 = pairs[j];
        uint2 p1 = pairs[j + 2];
        f32x4 y0 = ld_nt(y + (size_t)p0.x * DIM + col);
        f32x4 x0 = ld  (x + (size_t)p0.y * DIM + col);
        f32x4 y1 = ld_nt(y + (size_t)p1.x * DIM + col);
        f32x4 x1 = ld  (x + (size_t)p1.y * DIM + col);
        a0 += x0.x * y0.x; a1 += x0.y * y0.y; a2 += x0.z * y0.z; a3 += x0.w * y0.w;
        b0 += x1.x * y1.x; b1 += x1.y * y1.y; b2 += x1.z * y1.z; b3 += x1.w * y1.w;
    }
    if (j < end) {
        uint2 p0 = pairs[j];
        f32x4 y0 = ld_nt(y + (size_t)p0.x * DIM + col);
        f32x4 x0 = ld  (x + (size_t)p0.y * DIM + col);
        a0 += x0.x * y0.x; a1 += x0.y * y0.y; a2 += x0.z * y0.z; a3 += x0.w * y0.w;
    }

    a0 += b0; a1 += b1; a2 += b2; a3 += b3;
    // combine even/odd halves: lane l <-> lane l+32
    a0 += __shfl_xor(a0, 32, 64);
    a1 += __shfl_xor(a1, 32, 64);
    a2 += __shfl_xor(a2, 32, 64);
    a3 += __shfl_xor(a3, 32, 64);

    if (half == 0) {
        f32x4 r = { c * a0, c * a1, c * a2, c * a3 };
        __builtin_nontemporal_store(r, reinterpret_cast<f32x4*>(out + (size_t)n * DIM + col));
    }
}

extern "C" void kernel_launch(void* const* d_in, const int* in_sizes, int n_in,
                              void* d_out, int out_size, void* d_ws, size_t ws_size,
                              hipStream_t stream)
{
    const float* x      = (const float*)d_in[0];
    const float* y      = (const float*)d_in[1];
    const float* coeffs = (const float*)d_in[2];
    const int*   src    = (const int*)d_in[3];
    const int*   dst    = (const int*)d_in[4];
    float* out = (float*)d_out;

    unsigned* ws      = (unsigned*)d_ws;
    unsigned* counts  = ws + WS_COUNTS;
    unsigned* cursors = ws + WS_CURSORS;
    unsigned* ctr     = ws + WS_CTR;
    unsigned* offsets = ws + WS_OFFSETS;
    uint2*    pairs   = (uint2*)(ws + WS_PAIRS);

    // Zero counts + cursors + ctr (contiguous head of ws; ws is poisoned each call)
    hipMemsetAsync(d_ws, 0, WS_OFFSETS * sizeof(unsigned), stream);

    hist_kernel   <<<(N_EDGES + 255) / 256, 256, 0, stream>>>(dst, counts);
    alloc_offsets <<<(N_NODES + 255) / 256, 256, 0, stream>>>(counts, offsets, ctr);
    scatter_kernel<<<(N_EDGES + 255) / 256, 256, 0, stream>>>(dst, src, offsets, cursors, pairs);
    gather_reduce <<<(N_NODES + 3) / 4,     256, 0, stream>>>(x, y, coeffs, offsets, counts, pairs, out);
}